// Round 8
// baseline (38.007 us; speedup 1.0000x reference)
//
#include <hip/hip_runtime.h>
#include <hip/hip_bf16.h>
#include <math.h>

// RoIPooling2D: x (1, 256, 64, 64) fp32, rois (1, 512, 4) int32 [rx, ry, rw, rh]
// out (512, 256, 7, 7) fp32.
// dh = rh/7, dw = rw/7 in [1,4]; out[n,c,kb,jb] = max_{t<dh,s<dw} x[c, ry+dh*kb+t, rx+dw*jb+s]
// rx,ry <= 35 -> max index 62 < 64 -> clamps never fire.
//
// Round 8: channel-contiguous layout.
//  - kernel1: transpose x[256][4096] -> xT[4096][256] in d_ws (pos-major).
//    Every pooled read then has 64 lanes = 64 consecutive channels = 256 B
//    dense; window-position arithmetic is wave-uniform SGPR math.
//  - kernel2: block = (n, c-half). Threads <-> (kpart, c_local). dh/dw are
//    block-uniform (one roi per block) -> zero divergence, NO sorting needed.
//    Results staged in LDS [49][129] then written as one 25088-B contiguous,
//    line-exclusive, dense run per block.

#define HW 4096   // 64*64 positions

// ---------------- kernel 1: transpose ----------------
__global__ __launch_bounds__(256) void xpose_kernel(const float* __restrict__ x,
                                                    float* __restrict__ xT)
{
    __shared__ float tile[64][65];
    const int tid = threadIdx.x;
    const int pc = blockIdx.x & 63;    // position tile 0..63
    const int cc = blockIdx.x >> 6;    // channel tile 0..3
    const int p0 = pc << 6, c0 = cc << 6;
    const int jr  = tid & 63;          // lane within 64
    const int ir4 = tid >> 6;          // 0..3

    #pragma unroll
    for (int rr = 0; rr < 16; ++rr) {
        int ci = rr * 4 + ir4;                                  // 0..63
        tile[ci][jr] = x[(size_t)(c0 + ci) * HW + p0 + jr];     // dense read
    }
    __syncthreads();
    #pragma unroll
    for (int rr = 0; rr < 16; ++rr) {
        int pi = rr * 4 + ir4;                                  // 0..63
        // xT[pos][c] = x[c][pos]; lanes jr = consecutive c -> dense write.
        // LDS read tile[jr][pi]: addr = jr*65 + pi -> banks (jr+pi)%32, conflict-free.
        xT[(size_t)(p0 + pi) * 256 + c0 + jr] = tile[jr][pi];
    }
}

// ---------------- kernel 2: pool ----------------
template<int DW>
__device__ __forceinline__ void pool_compute(const float* __restrict__ xT,
                                             float* __restrict__ ldsout,
                                             int rx, int ry, int dh,
                                             int kb_lo, int kb_hi, int cl, int c)
{
    for (int kb = kb_lo; kb < kb_hi; ++kb) {       // wave-uniform trip count
        const int prow = ry + dh * kb;
        #pragma unroll
        for (int jb = 0; jb < 7; ++jb) {
            const int pcol = rx + DW * jb;
            const float* p = xT + (size_t)(prow * 64 + pcol) * 256 + c;
            float m = -INFINITY;
            for (int t = 0; t < dh; ++t) {         // wave-uniform
                #pragma unroll
                for (int s = 0; s < DW; ++s)       // imm offsets 0..3072 B
                    m = fmaxf(m, p[s * 256]);
                p += 64 * 256;                     // next window row
            }
            ldsout[(kb * 7 + jb) * 129 + cl] = m;  // lane-stride 1, conflict-free
        }
    }
}

__global__ __launch_bounds__(256) void roipool_kernel(const float* __restrict__ xT,
                                                      const int* __restrict__ rois,
                                                      float* __restrict__ out)
{
    __shared__ float ldsout[49 * 129];   // 25284 B -> 4 blocks/CU (grid-limited)

    const int bid = blockIdx.x;
    const int n   = bid >> 1;            // roi 0..511
    const int c0  = (bid & 1) << 7;      // channel half: 0 or 128
    const int tid = threadIdx.x;
    const int kpart = tid >> 7;          // 0: kb 0..3, 1: kb 4..6 (wave-uniform)
    const int cl  = tid & 127;           // channel within half
    const int c   = c0 + cl;

    const int4 r = ((const int4*)rois)[n];
    // roi is block-uniform: force into SGPRs so window math is scalar.
    const int rx = __builtin_amdgcn_readfirstlane(r.x);
    const int ry = __builtin_amdgcn_readfirstlane(r.y);
    const int dw = __builtin_amdgcn_readfirstlane(r.z) / 7;   // 1..4
    const int dh = __builtin_amdgcn_readfirstlane(r.w) / 7;   // 1..4

    const int kb_lo = kpart ? 4 : 0;
    const int kb_hi = kpart ? 7 : 4;

    switch (dw) {   // block-uniform branch
        case 1:  pool_compute<1>(xT, ldsout, rx, ry, dh, kb_lo, kb_hi, cl, c); break;
        case 2:  pool_compute<2>(xT, ldsout, rx, ry, dh, kb_lo, kb_hi, cl, c); break;
        case 3:  pool_compute<3>(xT, ldsout, rx, ry, dh, kb_lo, kb_hi, cl, c); break;
        default: pool_compute<4>(xT, ldsout, rx, ry, dh, kb_lo, kb_hi, cl, c); break;
    }
    __syncthreads();

    // copy-out: 128 c * 49 k = 6272 floats, contiguous + 64B-aligned at
    // (n*256 + c0)*196 B -> dense line-exclusive stores.
    float* outp = out + ((size_t)n * 256 + c0) * 49;
    for (int f = tid; f < 128 * 49; f += 256) {
        int cl2 = f / 49;
        int k2  = f - cl2 * 49;
        // LDS addr = k2*129 + cl2 -> banks (k2+cl2)%32 across lanes, ~conflict-free
        outp[f] = ldsout[k2 * 129 + cl2];
    }
}

extern "C" void kernel_launch(void* const* d_in, const int* in_sizes, int n_in,
                              void* d_out, int out_size, void* d_ws, size_t ws_size,
                              hipStream_t stream) {
    const float* x    = (const float*)d_in[0];
    const int*   rois = (const int*)d_in[1];
    float*       out  = (float*)d_out;
    float*       xT   = (float*)d_ws;    // 4096*256*4 = 4 MB scratch

    xpose_kernel<<<256, 256, 0, stream>>>(x, xT);
    // grid: 512 rois x 2 channel-halves
    roipool_kernel<<<1024, 256, 0, stream>>>(xT, rois, out);
}

// Round 9
// 20.202 us; speedup vs baseline: 1.8814x; 1.8814x over previous
//
#include <hip/hip_runtime.h>
#include <hip/hip_bf16.h>
#include <math.h>

// RoIPooling2D: x (1, 256, 64, 64) fp32, rois (1, 512, 4) int32 [rx, ry, rw, rh]
// out (512, 256, 7, 7) fp32.
// dh = rh/7, dw = rw/7 in [1,4]; out[n,c,kb,jb] = max_{t<dh,s<dw} x[c, ry+dh*kb+t, rx+dw*jb+s]
// rx,ry <= 35 -> max index 62 < 64 -> clamps never fire.
//
// Round 9: 4-channel-interleaved LDS slab, ds_read_b128 pool reads.
//  - kernel1 (1 block, PROVEN R4/R7): counting-sort rois by class ->
//    sdesc int4{rx, ry, cls, n} in d_ws. Output order-invariant.
//  - kernel2: grid 512 = (roi-group g 0..7 [64 rois], channel-quad 0..63);
//    448 threads; LDS = float4 slab[64*65] (65 KB) -> 2 blocks/CU exact.
//    * staging: lane owns position pos; reads 4 channels (4 dense 256B global
//      wave-reads); writes ONE float4 (b128, uniform bank-group spread).
//    * pool: thread = (roi, kb); template<DH,DW> body, SAME index algebra as
//      proven R4 scalar body but on float4 quads -> each b128 feeds 4 outputs.
//      4x fewer LDS wave-ops than R7.
//    * stores: direct b32; channels c0..c0+3 adjacent in out.

#define QS 65   // padded row stride in quads: bank-group = (row+col) % 8

// ---------------- kernel 1: sort (verbatim R4/R7, proven) ----------------
__global__ __launch_bounds__(512) void roi_sort_kernel(
    const int* __restrict__ rois, int4* __restrict__ sdesc)
{
    __shared__ int start[16];
    const int tid = threadIdx.x;
    if (tid < 16) start[tid] = 0;
    __syncthreads();
    const int4 r = ((const int4*)rois)[tid];
    const int dw = r.z / 7, dh = r.w / 7;          // 1..4
    const int cls = (dh - 1) * 4 + (dw - 1);       // 0..15
    atomicAdd(&start[cls], 1);
    __syncthreads();
    if (tid == 0) {
        int acc = 0;
        #pragma unroll
        for (int k = 0; k < 16; ++k) { int cnt = start[k]; start[k] = acc; acc += cnt; }
    }
    __syncthreads();
    const int pos = atomicAdd(&start[cls], 1);
    sdesc[pos] = make_int4(r.x, r.y, cls, tid);
}

// ---------------- kernel 2: pool ----------------
template<int DH, int DW>
__device__ __forceinline__ void pool_body4(const float4* __restrict__ slab,
                                           int ry, int rx, int kb,
                                           float4 m[7])
{
    const int a0 = (ry + DH * kb) * QS + rx;       // same algebra as proven R4 body
    #pragma unroll
    for (int t = 0; t < DH; ++t) {
        #pragma unroll
        for (int jb = 0; jb < 7; ++jb) {
            #pragma unroll
            for (int s = 0; s < DW; ++s) {
                const float4 v = slab[a0 + t * QS + DW * jb + s];
                m[jb].x = fmaxf(m[jb].x, v.x);
                m[jb].y = fmaxf(m[jb].y, v.y);
                m[jb].z = fmaxf(m[jb].z, v.z);
                m[jb].w = fmaxf(m[jb].w, v.w);
            }
        }
    }
}

__global__ __launch_bounds__(448) void roipool_kernel(
    const float* __restrict__ x,
    const int4*  __restrict__ sdesc,
    float*       __restrict__ out)
{
    __shared__ float4 slab[64 * QS];   // 66560 B -> 2 blocks/CU

    const int bid = blockIdx.x;
    const int c0  = (bid & 63) << 2;   // channel quad base: 0,4,...,252
    const int g   = bid >> 6;          // roi group 0..7 (64 sorted rois each)
    const int tid = threadIdx.x;

    // ---- preload this thread's descriptor (global sdesc, sorted)
    const int q0 = tid / 7;            // 0..63 local roi
    const int kb = tid - q0 * 7;       // 0..6
    const int4 d = sdesc[g * 64 + q0];

    // ---- stage 4-channel slab: lane owns pos; 4 dense global reads -> 1 b128 write
    const float* xb = x + (size_t)c0 * 4096;
    #pragma unroll
    for (int k = 0; k < 10; ++k) {
        int pos = tid + k * 448;
        if (pos < 4096) {
            float v0 = xb[pos];
            float v1 = xb[pos + 4096];
            float v2 = xb[pos + 8192];
            float v3 = xb[pos + 12288];
            // quad index = row*QS + col; wave spans one row -> uniform bank groups
            slab[(pos >> 6) * QS + (pos & 63)] = make_float4(v0, v1, v2, v3);
        }
    }
    __syncthreads();

    // ---- pool: wave-uniform switch (rois sorted by class)
    float4 m[7];
    #pragma unroll
    for (int j = 0; j < 7; ++j) m[j] = make_float4(-INFINITY, -INFINITY, -INFINITY, -INFINITY);

    switch (d.z) {
        case  0: pool_body4<1,1>(slab, d.y, d.x, kb, m); break;
        case  1: pool_body4<1,2>(slab, d.y, d.x, kb, m); break;
        case  2: pool_body4<1,3>(slab, d.y, d.x, kb, m); break;
        case  3: pool_body4<1,4>(slab, d.y, d.x, kb, m); break;
        case  4: pool_body4<2,1>(slab, d.y, d.x, kb, m); break;
        case  5: pool_body4<2,2>(slab, d.y, d.x, kb, m); break;
        case  6: pool_body4<2,3>(slab, d.y, d.x, kb, m); break;
        case  7: pool_body4<2,4>(slab, d.y, d.x, kb, m); break;
        case  8: pool_body4<3,1>(slab, d.y, d.x, kb, m); break;
        case  9: pool_body4<3,2>(slab, d.y, d.x, kb, m); break;
        case 10: pool_body4<3,3>(slab, d.y, d.x, kb, m); break;
        case 11: pool_body4<3,4>(slab, d.y, d.x, kb, m); break;
        case 12: pool_body4<4,1>(slab, d.y, d.x, kb, m); break;
        case 13: pool_body4<4,2>(slab, d.y, d.x, kb, m); break;
        case 14: pool_body4<4,3>(slab, d.y, d.x, kb, m); break;
        default: pool_body4<4,4>(slab, d.y, d.x, kb, m); break;
    }

    // ---- stores: 4 channels x 7 jb; channels adjacent in out (runs of 49)
    const int n = d.w;
    float* op = out + ((size_t)n * 256 + c0) * 49 + kb * 7;
    #pragma unroll
    for (int jb = 0; jb < 7; ++jb) {
        op[jb]       = m[jb].x;
        op[49 + jb]  = m[jb].y;
        op[98 + jb]  = m[jb].z;
        op[147 + jb] = m[jb].w;
    }
}

extern "C" void kernel_launch(void* const* d_in, const int* in_sizes, int n_in,
                              void* d_out, int out_size, void* d_ws, size_t ws_size,
                              hipStream_t stream) {
    const float* x    = (const float*)d_in[0];
    const int*   rois = (const int*)d_in[1];
    float*       out  = (float*)d_out;
    int4*        sdesc = (int4*)d_ws;   // 512 * 16 B = 8 KB scratch

    roi_sort_kernel<<<1, 512, 0, stream>>>(rois, sdesc);
    // grid: 8 roi-groups (bid>>6) x 64 channel-quads (bid&63)
    roipool_kernel<<<512, 448, 0, stream>>>(x, sdesc, out);
}

// Round 10
// 14.988 us; speedup vs baseline: 2.5358x; 1.3479x over previous
//
#include <hip/hip_runtime.h>
#include <hip/hip_bf16.h>
#include <math.h>

// RoIPooling2D: x (1, 256, 64, 64) fp32, rois (1, 512, 4) int32 [rx, ry, rw, rh]
// out (512, 256, 7, 7) fp32.
// dh = rh/7, dw = rw/7 in [1,4]; out[n,c,kb,jb] = max_{t<dh,s<dw} x[c, ry+dh*kb+t, rx+dw*jb+s]
// rx,ry <= 35 -> max index 62 < 64 -> clamps never fire.
//
// Round 10: one-roi-per-wave => divergence-free WITHOUT sorting; single kernel.
//  - grid 512 = (roi-group g 0..7 [64 rois], channel-quad 0..63); 512 threads
//    (8 waves); LDS = float4 slab[64*65] (65 KB) -> 2 blocks/CU exact.
//  - staging (proven R9): lane owns position; 4 dense 256B global reads ->
//    one b128 LDS write, conflict-free.
//  - pool: each wave serially processes 8 rois. Lanes 0..48 = the 49 (kb,jb)
//    cells; roi params broadcast to SGPRs -> wave-uniform template switch,
//    compile-time loop bounds, zero divergence, no sort, no sdesc.
//    Each ds_read_b128 feeds 4 channels of one cell.
//  - stores: lane l writes out[(n*256+c0)*49 + l] (+49/98/147) -> 4 dense
//    196-B runs per roi, fully coalesced, no outbuf.

#define QS 65   // padded row stride in quads

template<int DH, int DW>
__device__ __forceinline__ float4 pool4(const float4* __restrict__ slab, int qa)
{
    float4 m = make_float4(-INFINITY, -INFINITY, -INFINITY, -INFINITY);
    #pragma unroll
    for (int t = 0; t < DH; ++t) {
        #pragma unroll
        for (int s = 0; s < DW; ++s) {
            const float4 v = slab[qa + t * QS + s];   // imm offset <= 3168 B
            m.x = fmaxf(m.x, v.x);
            m.y = fmaxf(m.y, v.y);
            m.z = fmaxf(m.z, v.z);
            m.w = fmaxf(m.w, v.w);
        }
    }
    return m;
}

__global__ __launch_bounds__(512) void roipool_kernel(
    const float* __restrict__ x,
    const int*   __restrict__ rois,
    float*       __restrict__ out)
{
    __shared__ float4 slab[64 * QS];   // 66560 B -> 2 blocks/CU

    const int bid = blockIdx.x;
    const int c0  = (bid & 63) << 2;   // channel quad base
    const int g   = bid >> 6;          // roi group 0..7
    const int tid = threadIdx.x;

    // ---- stage 4-channel slab (R9 proven): dense reads, conflict-free b128 writes
    const float* xb = x + (size_t)c0 * 4096;
    #pragma unroll
    for (int k = 0; k < 8; ++k) {
        int pos = tid + k * 512;       // 4096 exact
        slab[(pos >> 6) * QS + (pos & 63)] =
            make_float4(xb[pos], xb[pos + 4096], xb[pos + 8192], xb[pos + 12288]);
    }
    __syncthreads();

    const int wv = tid >> 6;           // wave 0..7
    const int ln = tid & 63;           // lane
    const int kb = ln / 7;             // 0..6 for ln<49
    const int jb = ln - kb * 7;

    // ---- 8 rois per wave, one roi per iteration (wave-uniform everything)
    #pragma unroll
    for (int it = 0; it < 8; ++it) {
        const int n = g * 64 + wv * 8 + it;
        const int4 r = ((const int4*)rois)[n];
        const int rx = __builtin_amdgcn_readfirstlane(r.x);
        const int ry = __builtin_amdgcn_readfirstlane(r.y);
        const int dw = __builtin_amdgcn_readfirstlane(r.z) / 7;   // 1..4
        const int dh = __builtin_amdgcn_readfirstlane(r.w) / 7;   // 1..4
        const int cls = (dh - 1) * 4 + (dw - 1);                  // scalar

        if (ln < 49) {
            const int qa = (ry + dh * kb) * QS + rx + dw * jb;    // per-lane base
            float4 m;
            switch (cls) {   // wave-uniform branch
                case  0: m = pool4<1,1>(slab, qa); break;
                case  1: m = pool4<1,2>(slab, qa); break;
                case  2: m = pool4<1,3>(slab, qa); break;
                case  3: m = pool4<1,4>(slab, qa); break;
                case  4: m = pool4<2,1>(slab, qa); break;
                case  5: m = pool4<2,2>(slab, qa); break;
                case  6: m = pool4<2,3>(slab, qa); break;
                case  7: m = pool4<2,4>(slab, qa); break;
                case  8: m = pool4<3,1>(slab, qa); break;
                case  9: m = pool4<3,2>(slab, qa); break;
                case 10: m = pool4<3,3>(slab, qa); break;
                case 11: m = pool4<3,4>(slab, qa); break;
                case 12: m = pool4<4,1>(slab, qa); break;
                case 13: m = pool4<4,2>(slab, qa); break;
                case 14: m = pool4<4,3>(slab, qa); break;
                default: m = pool4<4,4>(slab, qa); break;
            }
            // coalesced: lane l -> out[... + l]; 4 dense 196-B runs per roi
            float* op = out + ((size_t)n * 256 + c0) * 49 + ln;
            op[0]   = m.x;
            op[49]  = m.y;
            op[98]  = m.z;
            op[147] = m.w;
        }
    }
}

extern "C" void kernel_launch(void* const* d_in, const int* in_sizes, int n_in,
                              void* d_out, int out_size, void* d_ws, size_t ws_size,
                              hipStream_t stream) {
    const float* x    = (const float*)d_in[0];
    const int*   rois = (const int*)d_in[1];
    float*       out  = (float*)d_out;

    // grid: 8 roi-groups (bid>>6) x 64 channel-quads (bid&63)
    roipool_kernel<<<512, 512, 0, stream>>>(x, rois, out);
}

// Round 11
// 14.006 us; speedup vs baseline: 2.7136x; 1.0701x over previous
//
#include <hip/hip_runtime.h>
#include <hip/hip_bf16.h>
#include <math.h>

// RoIPooling2D: x (1, 256, 64, 64) fp32, rois (1, 512, 4) int32 [rx, ry, rw, rh]
// out (512, 256, 7, 7) fp32.
// dh = rh/7, dw = rw/7 in [1,4]; out[n,c,kb,jb] = max_{t<dh,s<dw} x[c, ry+dh*kb+t, rx+dw*jb+s]
// rx,ry <= 35 -> max index 62 < 64 -> clamps never fire.
//
// Round 11 = R10 (proven, 15.0 us) + LDS bank-conflict fix on pool reads.
//  - R10 structure: single kernel; grid 512 = (roi-group g, channel-quad);
//    512 threads; float4 slab[64*65] (65 KB, 2 blocks/CU); one roi per wave
//    per iteration (wave-uniform class switch, zero divergence, no sort);
//    stores = 4 dense 196-B runs per roi.
//  - NEW: per-lane rotation of the window-row loop for DH in {2,4}:
//      t = (i + ln) & (DH-1)
//    Rotation is a bijection over t-values per lane (max unchanged), but one
//    instruction now reads DIFFERENT window rows across lanes:
//    bank-group = 4*parity(kb+jb) + (i+ln)&3 spans all 8 groups (~6 lanes/grp,
//    the structural floor for 49 lanes) instead of {0,4} (25 lanes/grp) for
//    class (4,4). Odd DH classes already spread via kb (coeff odd mod 8).
//  - NEW: all 8 roi int4 loads hoisted before staging (latency overlap).

#define QS 65   // padded row stride in quads

template<int DH, int DW>
__device__ __forceinline__ float4 pool4(const float4* __restrict__ slab,
                                        int qa, int ln)
{
    float4 m = make_float4(-INFINITY, -INFINITY, -INFINITY, -INFINITY);
    #pragma unroll
    for (int i = 0; i < DH; ++i) {
        // pow2 DH: rotate row order per-lane (bijective); odd DH: plain order
        const int t = ((DH & (DH - 1)) == 0) ? ((i + ln) & (DH - 1)) : i;
        const float4* p = slab + qa + t * QS;
        #pragma unroll
        for (int s = 0; s < DW; ++s) {              // imm offsets
            const float4 v = p[s];
            m.x = fmaxf(m.x, v.x);
            m.y = fmaxf(m.y, v.y);
            m.z = fmaxf(m.z, v.z);
            m.w = fmaxf(m.w, v.w);
        }
    }
    return m;
}

__global__ __launch_bounds__(512) void roipool_kernel(
    const float* __restrict__ x,
    const int*   __restrict__ rois,
    float*       __restrict__ out)
{
    __shared__ float4 slab[64 * QS];   // 66560 B -> 2 blocks/CU

    const int bid = blockIdx.x;
    const int c0  = (bid & 63) << 2;   // channel quad base
    const int g   = bid >> 6;          // roi group 0..7
    const int tid = threadIdx.x;
    const int wv  = tid >> 6;          // wave 0..7
    const int ln  = tid & 63;          // lane

    // ---- hoist all 8 roi descriptors (independent loads; latency overlaps staging)
    int4 rr[8];
    #pragma unroll
    for (int it = 0; it < 8; ++it)
        rr[it] = ((const int4*)rois)[g * 64 + wv * 8 + it];

    // ---- stage 4-channel slab (R9/R10 proven): dense reads, conflict-free b128 writes
    const float* xb = x + (size_t)c0 * 4096;
    #pragma unroll
    for (int k = 0; k < 8; ++k) {
        int pos = tid + k * 512;       // 4096 exact
        slab[(pos >> 6) * QS + (pos & 63)] =
            make_float4(xb[pos], xb[pos + 4096], xb[pos + 8192], xb[pos + 12288]);
    }
    __syncthreads();

    const int kb = ln / 7;             // 0..6 for ln<49
    const int jb = ln - kb * 7;

    // ---- 8 rois per wave, one roi per iteration (wave-uniform everything)
    #pragma unroll
    for (int it = 0; it < 8; ++it) {
        const int n = g * 64 + wv * 8 + it;
        const int4 r = rr[it];
        const int rx = __builtin_amdgcn_readfirstlane(r.x);
        const int ry = __builtin_amdgcn_readfirstlane(r.y);
        const int dw = __builtin_amdgcn_readfirstlane(r.z) / 7;   // 1..4
        const int dh = __builtin_amdgcn_readfirstlane(r.w) / 7;   // 1..4
        const int cls = (dh - 1) * 4 + (dw - 1);                  // scalar

        if (ln < 49) {
            const int qa = (ry + dh * kb) * QS + rx + dw * jb;    // per-lane base
            float4 m;
            switch (cls) {   // wave-uniform branch
                case  0: m = pool4<1,1>(slab, qa, ln); break;
                case  1: m = pool4<1,2>(slab, qa, ln); break;
                case  2: m = pool4<1,3>(slab, qa, ln); break;
                case  3: m = pool4<1,4>(slab, qa, ln); break;
                case  4: m = pool4<2,1>(slab, qa, ln); break;
                case  5: m = pool4<2,2>(slab, qa, ln); break;
                case  6: m = pool4<2,3>(slab, qa, ln); break;
                case  7: m = pool4<2,4>(slab, qa, ln); break;
                case  8: m = pool4<3,1>(slab, qa, ln); break;
                case  9: m = pool4<3,2>(slab, qa, ln); break;
                case 10: m = pool4<3,3>(slab, qa, ln); break;
                case 11: m = pool4<3,4>(slab, qa, ln); break;
                case 12: m = pool4<4,1>(slab, qa, ln); break;
                case 13: m = pool4<4,2>(slab, qa, ln); break;
                case 14: m = pool4<4,3>(slab, qa, ln); break;
                default: m = pool4<4,4>(slab, qa, ln); break;
            }
            // coalesced: lane l -> out[... + l]; 4 dense 196-B runs per roi
            float* op = out + ((size_t)n * 256 + c0) * 49 + ln;
            op[0]   = m.x;
            op[49]  = m.y;
            op[98]  = m.z;
            op[147] = m.w;
        }
    }
}

extern "C" void kernel_launch(void* const* d_in, const int* in_sizes, int n_in,
                              void* d_out, int out_size, void* d_ws, size_t ws_size,
                              hipStream_t stream) {
    const float* x    = (const float*)d_in[0];
    const int*   rois = (const int*)d_in[1];
    float*       out  = (float*)d_out;

    // grid: 8 roi-groups (bid>>6) x 64 channel-quads (bid&63)
    roipool_kernel<<<512, 512, 0, stream>>>(x, rois, out);
}